// Round 1
// baseline (266.726 us; speedup 1.0000x reference)
//
#include <hip/hip_runtime.h>

typedef __attribute__((ext_vector_type(4))) float f32x4;
typedef __attribute__((ext_vector_type(8))) short s16x8;  // 8 x bf16 fragment

#define DEVI static __device__ __forceinline__

constexpr int BB = 4, HH = 8, TT = 2048, DD = 256;

// fp32 -> bf16 round-to-nearest-even (no NaN handling; inputs are Gaussian)
DEVI short f2bf(float f) {
  union { float f; unsigned u; } x; x.f = f;
  unsigned r = x.u + 0x7fffu + ((x.u >> 16) & 1u);
  return (short)(r >> 16);
}

// ---------------------------------------------------------------------------
// Kernel 1: cast r' -> rbf, Q -> Qt (transposed, bf16), E -> Ebf
// ---------------------------------------------------------------------------
__global__ void cast_prep(const float* __restrict__ r, const float* __restrict__ Q,
                          const float* __restrict__ E,
                          short* __restrict__ rbf, short* __restrict__ Qt,
                          short* __restrict__ Ebf) {
  int idx = blockIdx.x * blockDim.x + threadIdx.x;
  int stride = gridDim.x * blockDim.x;
  for (int i = idx; i < BB * TT * DD; i += stride) rbf[i] = f2bf(r[i]);
  for (int i = idx; i < HH * DD * DD; i += stride) {
    int h = i / (DD * DD), rem = i % (DD * DD), j = rem / DD, i2 = rem % DD;
    Qt[i] = f2bf(Q[(h * DD + i2) * DD + j]);  // Qt[h][j][i2] = Q[h][i2][j]
    Ebf[i] = f2bf(E[i]);
  }
}

// ---------------------------------------------------------------------------
// Kernel 2: C[M][N] = X[M][K=256] @ W[N][K]^T  (bf16 in, fp32 acc, bf16 out)
// mode 0: X=rbf[b] (M=2048), W=Qt[h] (N=256)  -> Abf[b][h][t][j]
// mode 1: X=Ebf[h] (M=256),  W=rbf[b] (N=2048) -> Vt[b][h][i][u]
// ---------------------------------------------------------------------------
__global__ __launch_bounds__(256, 2)
void prep_gemm(const short* __restrict__ rbf, const short* __restrict__ Qt,
               const short* __restrict__ Ebf, short* __restrict__ Abf,
               short* __restrict__ Vtbf, int mode) {
  __shared__ __align__(16) short w_lds[64 * 256];
  int tid = threadIdx.x, lane = tid & 63, wid = tid >> 6;
  int h = blockIdx.y, b = blockIdx.z, bx = blockIdx.x;
  const short* X; const short* W; short* C; int ldC, m0, n0;
  if (mode == 0) {
    m0 = (bx >> 2) * 64; n0 = (bx & 3) * 64;
    X = rbf + (size_t)b * TT * DD;
    W = Qt + (size_t)h * DD * DD;
    C = Abf + (size_t)(b * HH + h) * TT * DD; ldC = DD;
  } else {
    m0 = (bx & 3) * 64; n0 = (bx >> 2) * 64;
    X = Ebf + (size_t)h * DD * DD;
    W = rbf + (size_t)b * TT * DD;
    C = Vtbf + (size_t)(b * HH + h) * DD * TT; ldC = TT;
  }
  // stage W rows n0..n0+63, XOR-swizzled in 16B blocks: blk' = blk ^ (row&7)
  #pragma unroll
  for (int it = 0; it < 8; ++it) {
    int t = it * 256 + tid;
    int row = t >> 5, kb = t & 31;
    s16x8 v = *(const s16x8*)(W + (size_t)(n0 + row) * DD + kb * 8);
    *(s16x8*)(&w_lds[row * 256 + ((kb ^ (row & 7)) << 3)]) = v;
  }
  // X fragments (A operand): row = m0+wid*16+(lane&15), k = ks*32+(lane>>4)*8+e
  s16x8 a[8];
  {
    const short* xrow = X + (size_t)(m0 + wid * 16 + (lane & 15)) * DD + (lane >> 4) * 8;
    #pragma unroll
    for (int ks = 0; ks < 8; ++ks) a[ks] = *(const s16x8*)(xrow + ks * 32);
  }
  __syncthreads();
  f32x4 c[4] = {};
  #pragma unroll
  for (int n = 0; n < 4; ++n) {
    int row = n * 16 + (lane & 15);
    #pragma unroll
    for (int ks = 0; ks < 8; ++ks) {
      int kb = ks * 4 + (lane >> 4);
      s16x8 bfr = *(const s16x8*)(&w_lds[row * 256 + ((kb ^ (row & 7)) << 3)]);
      c[n] = __builtin_amdgcn_mfma_f32_16x16x32_bf16(a[ks], bfr, c[n], 0, 0, 0);
    }
  }
  // C/D layout: row = (lane>>4)*4 + reg, col = lane&15 (m89-verified)
  #pragma unroll
  for (int n = 0; n < 4; ++n) {
    int col = n0 + n * 16 + (lane & 15);
    #pragma unroll
    for (int rr = 0; rr < 4; ++rr) {
      int row = m0 + wid * 16 + (lane >> 4) * 4 + rr;
      C[(size_t)row * ldC + col] = f2bf(c[n][rr]);
    }
  }
}

// ---------------------------------------------------------------------------
// Kernel 3: flash-style causal main loop, per (b, h, t-tile of 64 rows).
// out[b][t][i] += sum_{u<=t} S[t][u] * V[u][i]   (atomic head-sum)
// ---------------------------------------------------------------------------
__global__ __launch_bounds__(256, 2)
void attn_main(const short* __restrict__ Abf, const short* __restrict__ Kbf,
               const short* __restrict__ Vtb, float* __restrict__ out) {
  __shared__ __align__(16) short k_lds[64 * 256];   // K tile [u][j], swizzled
  __shared__ __align__(16) short v_lds[256 * 64];   // Vt tile [i][u], swizzled
  __shared__ __align__(16) short s_lds[64 * 64];    // S tile  [t][u], swizzled
  int tid = threadIdx.x, lane = tid & 63, wid = tid >> 6;
  int t0 = blockIdx.x * 64, h = blockIdx.y, b = blockIdx.z;

  const short* Ab = Abf + ((size_t)(b * HH + h) * TT + t0) * DD;
  const short* Kb = Kbf + (size_t)b * TT * DD;
  const short* Vb = Vtb + (size_t)(b * HH + h) * DD * TT;

  // A fragments for this wave's 16 t-rows, all of K=256 (held for whole loop)
  s16x8 a[8];
  {
    const short* arow = Ab + (size_t)(wid * 16 + (lane & 15)) * DD + (lane >> 4) * 8;
    #pragma unroll
    for (int ks = 0; ks < 8; ++ks) a[ks] = *(const s16x8*)(arow + ks * 32);
  }
  f32x4 acc[16] = {};  // 16 rows x 256 i-cols per wave

  int nU = t0 / 64 + 1;
  for (int iu = 0; iu < nU; ++iu) {
    int U = iu * 64;
    __syncthreads();
    {
      // stage K rows U..U+63 (64x256 bf16, 32KB)
      const short* src = Kb + (size_t)U * DD;
      #pragma unroll
      for (int it = 0; it < 8; ++it) {
        int t = it * 256 + tid;
        int row = t >> 5, kb = t & 31;
        s16x8 v = *(const s16x8*)(src + (size_t)row * DD + kb * 8);
        *(s16x8*)(&k_lds[row * 256 + ((kb ^ (row & 7)) << 3)]) = v;
      }
      // stage Vt rows 0..255, cols U..U+63 (256x64 bf16, 32KB)
      const short* vsrc = Vb + U;
      #pragma unroll
      for (int it = 0; it < 8; ++it) {
        int t = it * 256 + tid;
        int row = t >> 3, cb = t & 7;
        s16x8 v = *(const s16x8*)(vsrc + (size_t)row * TT + cb * 8);
        *(s16x8*)(&v_lds[row * 64 + ((cb ^ (row & 7)) << 3)]) = v;
      }
    }
    __syncthreads();

    // S = A @ K^T  (4 u-subtiles x 8 k-steps)
    f32x4 s[4] = {};
    #pragma unroll
    for (int n = 0; n < 4; ++n) {
      int row = n * 16 + (lane & 15);
      #pragma unroll
      for (int ks = 0; ks < 8; ++ks) {
        int kb = ks * 4 + (lane >> 4);
        s16x8 bfr = *(const s16x8*)(&k_lds[row * 256 + ((kb ^ (row & 7)) << 3)]);
        s[n] = __builtin_amdgcn_mfma_f32_16x16x32_bf16(a[ks], bfr, s[n], 0, 0, 0);
      }
    }
    // causal mask + bf16 convert + write to per-wave S region (swizzled)
    int trow_base = t0 + wid * 16 + (lane >> 4) * 4;
    #pragma unroll
    for (int n = 0; n < 4; ++n) {
      int u_col = U + n * 16 + (lane & 15);
      #pragma unroll
      for (int rr = 0; rr < 4; ++rr) {
        float v = (u_col <= trow_base + rr) ? s[n][rr] : 0.0f;
        int srow = (lane >> 4) * 4 + rr;
        int scol = n * 16 + (lane & 15);
        s_lds[(wid * 16 + srow) * 64 + (((scol >> 3) ^ (srow & 7)) << 3) + (scol & 7)] = f2bf(v);
      }
    }
    // per-wave region: no barrier needed (compiler inserts lgkmcnt waits)

    // out_tile += S @ V : A-frag from s_lds, B-frag from v_lds
    #pragma unroll
    for (int ks = 0; ks < 2; ++ks) {
      int srow = lane & 15;
      int kb = ks * 4 + (lane >> 4);
      s16x8 af = *(const s16x8*)(&s_lds[(wid * 16 + srow) * 64 + ((kb ^ (srow & 7)) << 3)]);
      #pragma unroll
      for (int ni = 0; ni < 16; ++ni) {
        int vrow = ni * 16 + (lane & 15);
        s16x8 bfr = *(const s16x8*)(&v_lds[vrow * 64 + ((kb ^ (vrow & 7)) << 3)]);
        acc[ni] = __builtin_amdgcn_mfma_f32_16x16x32_bf16(af, bfr, acc[ni], 0, 0, 0);
      }
    }
  }

  // epilogue: head-sum via atomics
  float* ob = out + ((size_t)b * TT + t0 + wid * 16) * DD;
  #pragma unroll
  for (int ni = 0; ni < 16; ++ni) {
    int col = ni * 16 + (lane & 15);
    #pragma unroll
    for (int rr = 0; rr < 4; ++rr) {
      int row = (lane >> 4) * 4 + rr;
      atomicAdd(&ob[row * DD + col], acc[ni][rr]);
    }
  }
}

// ---------------------------------------------------------------------------
extern "C" void kernel_launch(void* const* d_in, const int* in_sizes, int n_in,
                              void* d_out, int out_size, void* d_ws, size_t ws_size,
                              hipStream_t stream) {
  const float* r = (const float*)d_in[0];
  const float* Q = (const float*)d_in[1];
  const float* E = (const float*)d_in[2];
  float* out = (float*)d_out;
  char* ws = (char*)d_ws;

  size_t off = 0;
  short* rbf = (short*)(ws + off); off += (size_t)BB * TT * DD * 2;   // 4 MiB
  short* Qt  = (short*)(ws + off); off += (size_t)HH * DD * DD * 2;   // 1 MiB
  short* Ebf = (short*)(ws + off); off += (size_t)HH * DD * DD * 2;   // 1 MiB
  short* Abf = (short*)(ws + off); off += (size_t)BB * HH * TT * DD * 2; // 32 MiB
  short* Vtb = (short*)(ws + off); off += (size_t)BB * HH * DD * TT * 2; // 32 MiB

  hipMemsetAsync(d_out, 0, (size_t)out_size * sizeof(float), stream);
  cast_prep<<<1024, 256, 0, stream>>>(r, Q, E, rbf, Qt, Ebf);
  prep_gemm<<<dim3(128, HH, BB), 256, 0, stream>>>(rbf, Qt, Ebf, Abf, Vtb, 0);
  prep_gemm<<<dim3(128, HH, BB), 256, 0, stream>>>(rbf, Qt, Ebf, Abf, Vtb, 1);
  attn_main<<<dim3(TT / 64, HH, BB), 256, 0, stream>>>(Abf, rbf, Vtb, out);
}